// Round 9
// baseline (1023.110 us; speedup 1.0000x reference)
//
#include <hip/hip_runtime.h>

#define NBK     64
#define GRID    4096
#define NPTS    512
#define NITER   100
#define WIN     7        // |d|<=3 window (WIN=5 failed w_dist)
#define ROWS_T  4        // rows per thread-half (h=0: rows 0-3, h=1: rows 4-6 +pad)
#define THREADS 1024
#define CPT     4
#define SPAN    24                 // pairs per thread, rank-partitioned
#define SLOTS   (THREADS * SPAN)   // 24576 >= provable worst case 23040
#define NTGT    6144               // flush targets <= 4096 nonempty + 1024 straddles
#define KTHR    1e-33f             // corner stamps K <= e^-80 always dropped
#define UTOL    1e-5f

// pair encoding: f32 K with its 9 low mantissa bits replaced by the point
// index. K rel-err <= 2^-15, full exponent range (f16 flush broke ot_obj in R2).
__device__ __forceinline__ unsigned int enc_pair(float K, int p) {
  unsigned int bits = __float_as_uint(K);
  bits = (bits + 0x100u) & 0xFFFFFE00u;
  return bits | (unsigned int)p;
}
__device__ __forceinline__ float dec_K(unsigned int w) {
  return __uint_as_float(w & 0xFFFFFE00u);
}

// exclusive block scan of one u32 per thread (2 internal barriers)
__device__ __forceinline__ unsigned int block_excl_scan(unsigned int val,
    unsigned int* s_wpart, int tid, int lane, int wid) {
  unsigned int inc = val;
  #pragma unroll
  for (int off = 1; off < 64; off <<= 1) {
    const unsigned int n = __shfl_up(inc, off, 64);
    if (lane >= off) inc += n;
  }
  if (lane == 63) s_wpart[wid] = inc;
  __syncthreads();
  if (tid == 0) {
    unsigned int run = 0;
    #pragma unroll
    for (int w = 0; w < THREADS / 64; ++w) {
      const unsigned int t = s_wpart[w];
      s_wpart[w] = run; run += t;
    }
  }
  __syncthreads();
  return s_wpart[wid] + inc - val;
}

__device__ __forceinline__ void block_reduce4(double* r, double* s_red,
                                              int tid, int lane, int wid) {
  #pragma unroll
  for (int off = 32; off >= 1; off >>= 1) {
    #pragma unroll
    for (int j = 0; j < 4; ++j) r[j] += __shfl_down(r[j], off, 64);
  }
  __syncthreads();
  if (lane == 0) {
    #pragma unroll
    for (int j = 0; j < 4; ++j) s_red[wid * 4 + j] = r[j];
  }
  __syncthreads();
  if (tid == 0) {
    double t0 = 0, t1 = 0, t2 = 0, t3 = 0;
    #pragma unroll
    for (int w = 0; w < THREADS / 64; ++w) {
      t0 += s_red[w * 4 + 0]; t1 += s_red[w * 4 + 1];
      t2 += s_red[w * 4 + 2]; t3 += s_red[w * 4 + 3];
    }
    s_red[64] = t0; s_red[65] = t1; s_red[66] = t2; s_red[67] = t3;
  }
  __syncthreads();
  r[0] = s_red[64]; r[1] = s_red[65]; r[2] = s_red[66]; r[3] = s_red[67];
}

extern "C" __global__ void __launch_bounds__(THREADS)
ot_loss_kernel(const float* __restrict__ pred,
               const float* __restrict__ normed,
               const float* __restrict__ pts,
               float* __restrict__ out)
{
  __shared__ unsigned int   s_pairs[SLOTS];  // transposed pair stream
  __shared__ float          s_v[GRID];       // v (u32 overlay: CSR cursors/ends)
  __shared__ float          s_ktu[GRID];     // KTu accum (u32 overlay: histograms)
  __shared__ float          s_u[NPTS];       // u (u32 overlay: sort perm)
  __shared__ unsigned short s_tgt[NTGT];     // flush-target cells, stream order
  __shared__ unsigned int   s_wpart[16];
  __shared__ double         s_red[68];

  const int b    = blockIdx.x;
  const int tid  = threadIdx.x;
  const int p    = tid >> 1;         // NEW point index (2 threads/point, post-sort)
  const int h    = tid & 1;
  const int lane = tid & 63, wid = tid >> 6;
  const int c0   = tid * CPT;        // this thread's 4 cells (blocked, 16B-aligned)

  const float* __restrict__ nrm_g  = normed + (size_t)b * GRID;
  const float* __restrict__ pred_g = pred   + (size_t)b * GRID;

  unsigned int* histU = (unsigned int*)s_ktu;  // histogram / count overlay
  unsigned int* curU  = (unsigned int*)s_v;    // cursor->end overlay
  unsigned int* permU = (unsigned int*)s_u;    // sort perm overlay

  // normed for my 4 cells lives in REGISTERS across all iterations
  const float4 nm = *reinterpret_cast<const float4*>(&nrm_g[c0]);

  #pragma unroll
  for (int q = 0; q < CPT; ++q) histU[c0 + q] = 0u;

  // ---- sort 1: histogram of home cells (OLD point order) ----
  const int p_old0 = p;
  const float2 ptO = ((const float2*)pts)[(size_t)b * NPTS + p_old0];
  const int homeO = ((int)(ptO.y * 0.125f)) * NBK + (int)(ptO.x * 0.125f);
  __syncthreads();
  if (h == 0) atomicAdd(&histU[homeO], 1u);
  __syncthreads();

  // ---- sort 2: scan home counts -> cell bases (cursors in curU) ----
  {
    unsigned int hc[CPT];
    #pragma unroll
    for (int q = 0; q < CPT; ++q) hc[q] = histU[c0 + q];
    const unsigned int ts = hc[0] + hc[1] + hc[2] + hc[3];
    unsigned int runb = block_excl_scan(ts, s_wpart, tid, lane, wid);
    #pragma unroll
    for (int q = 0; q < CPT; ++q) { curU[c0 + q] = runb; runb += hc[q]; }
  }
  __syncthreads();

  // ---- sort 3: scatter perm[new]=old ----
  if (h == 0) {
    const unsigned int dst = atomicAdd(&curU[homeO], 1u);
    permU[dst] = (unsigned int)p_old0;
  }
  __syncthreads();

  // ---- re-read own (sorted) point; window registers ----
  const unsigned int p_old = permU[p];
  const float2 pt = ((const float2*)pts)[(size_t)b * NPTS + p_old];
  const float x = pt.x, y = pt.y;
  const float x2 = x * x, y2 = y * y;
  const float m2x = -2.0f * x, m2y = -2.0f * y;
  const int jn  = (int)(y * 0.125f);
  const int in0 = (int)(x * 0.125f);

  float kx[WIN]; int colc[WIN];
  #pragma unroll
  for (int i = 0; i < WIN; ++i) {
    const int ii = in0 - 3 + i;
    const float cx = 8.0f * ii + 4.0f;
    const float xd = (m2x * cx + x2) + cx * cx;   // reference rounding order
    kx[i]   = (ii >= 0 && ii < NBK) ? expf(-xd / 10.0f) : 0.0f;
    colc[i] = (ii < 0 ? 0 : (ii > NBK - 1 ? NBK - 1 : ii));
  }
  const int r0 = h ? 4 : 0;
  float ky[ROWS_T]; int rowb[ROWS_T];
  #pragma unroll
  for (int k = 0; k < ROWS_T; ++k) {
    const int ko = r0 + k;
    const int j  = jn - 3 + ko;
    const float cy = 8.0f * j + 4.0f;
    const float yd = (m2y * cy + y2) + cy * cy;
    const bool ok = (ko < WIN) && (j >= 0) && (j < NBK);
    ky[k]   = ok ? expf(-yd / 10.0f) : 0.0f;
    rowb[k] = (j < 0 ? 0 : (j > NBK - 1 ? NBK - 1 : j)) * NBK;
  }

  // ---- filtered per-cell counts ----
  #pragma unroll
  for (int q = 0; q < CPT; ++q) histU[c0 + q] = 0u;
  __syncthreads();
  #pragma unroll
  for (int k = 0; k < ROWS_T; ++k) {
    #pragma unroll
    for (int i = 0; i < WIN; ++i) {
      const float K = ky[k] * kx[i];
      if (K >= KTHR) atomicAdd(&histU[rowb[k] + colc[i]], 1u);
    }
  }
  __syncthreads();

  // ---- scan counts -> CSR begin cursors ----
  {
    unsigned int cc[CPT];
    #pragma unroll
    for (int q = 0; q < CPT; ++q) cc[q] = histU[c0 + q];
    const unsigned int ts = cc[0] + cc[1] + cc[2] + cc[3];
    unsigned int runc = block_excl_scan(ts, s_wpart, tid, lane, wid);
    #pragma unroll
    for (int q = 0; q < CPT; ++q) { curU[c0 + q] = runc; runc += cc[q]; }
  }
  if (h == 0) s_u[p] = 1.0f / NPTS;   // perm consumed above; u live from here
  __syncthreads();

  // ---- zero pair slots (dummies decode K=0,p=0) ----
  #pragma unroll
  for (int r = 0; r < SPAN; ++r) s_pairs[(r << 10) + tid] = 0u;
  __syncthreads();

  // ---- fill pairs (transposed: rank g -> slot (g%SPAN)*1024 + g/SPAN) ----
  #pragma unroll
  for (int k = 0; k < ROWS_T; ++k) {
    #pragma unroll
    for (int i = 0; i < WIN; ++i) {
      const float K = ky[k] * kx[i];
      if (K >= KTHR) {
        const unsigned int g = atomicAdd(&curU[rowb[k] + colc[i]], 1u);
        const unsigned int t = g / SPAN, r = g % SPAN;
        s_pairs[(r << 10) + t] = enc_pair(K, p);
      }
    }
  }
  __syncthreads();
  // curU[c] is now end[c] (monotone, end[GRID-1] == totalReal)

  const unsigned int totalReal = curU[GRID - 1];
  const unsigned int g0 = (unsigned int)(tid * SPAN);

  // ---- derive run-end bitmask + flush count ----
  unsigned int my_mask = 0, nflush = 0;
  int cstart = 0;
  if (g0 < totalReal) {
    int lo = 0, hi = GRID - 1;
    while (lo < hi) { const int mid = (lo + hi) >> 1;
      if (curU[mid] > g0) hi = mid; else lo = mid + 1; }
    cstart = lo;
    int c = cstart;
    for (int r = 0; r < SPAN; ++r) {
      const unsigned int g = g0 + r;
      if (g >= totalReal) break;
      while (curU[c] <= g) ++c;
      if (g + 1 == curU[c] || r == SPAN - 1) { my_mask |= 1u << r; ++nflush; }
    }
  }
  const unsigned int my_tc = block_excl_scan(nflush, s_wpart, tid, lane, wid);
  // ---- second walk: write flush-target cells; zero KTu for iter 1 ----
  if (g0 < totalReal) {
    int c = cstart; unsigned int k = 0;
    for (int r = 0; r < SPAN; ++r) {
      const unsigned int g = g0 + r;
      if (g >= totalReal) break;
      while (curU[c] <= g) ++c;
      if (my_mask & (1u << r)) s_tgt[my_tc + k++] = (unsigned short)c;
    }
  }
  #pragma unroll
  for (int q = 0; q < CPT; ++q) s_ktu[c0 + q] = 0.0f;
  float u = 1.0f / NPTS;
  float u1 = u;
  int allok_prev = 0;
  const bool wave_live = ((unsigned int)((tid & ~63) * SPAN) < totalReal);
  __syncthreads();

  // ======== Sinkhorn loop: balanced spans, conflict-free stream, 3 barriers ========
  for (int it = 0; it < NITER; ++it) {
    // A: segmented KTu accumulation over rank-partitioned pair stream
    if (wave_live) {
      float acc = 0.0f; unsigned int tc = my_tc;
      #pragma unroll
      for (int r = 0; r < SPAN; ++r) {
        const unsigned int w = s_pairs[(r << 10) + tid];   // stride-1: conflict-free
        acc = fmaf(dec_K(w), s_u[w & 511u], acc);
        if (my_mask & (1u << r)) {
          atomicAdd(&s_ktu[s_tgt[tc]], acc); ++tc; acc = 0.0f;
        }
      }
    }
    __syncthreads();

    // B: v = nrm/(KTu+eps); re-zero KTu
    {
      const float4 kt = *reinterpret_cast<const float4*>(&s_ktu[c0]);
      float4 vv;
      vv.x = nm.x / (kt.x + 1e-16f);
      vv.y = nm.y / (kt.y + 1e-16f);
      vv.z = nm.z / (kt.z + 1e-16f);
      vv.w = nm.w / (kt.w + 1e-16f);
      *reinterpret_cast<float4*>(&s_v[c0]) = vv;
      *reinterpret_cast<float4*>(&s_ktu[c0]) = make_float4(0.f, 0.f, 0.f, 0.f);
    }
    __syncthreads();

    // C: Kv window gather; u update; publish
    float kv = 0.0f;
    #pragma unroll
    for (int k = 0; k < ROWS_T; ++k) {
      float s = 0.0f;
      const float* vrow = &s_v[rowb[k]];
      #pragma unroll
      for (int i = 0; i < WIN; ++i)
        s = fmaf(kx[i], vrow[colc[i]], s);
      kv = fmaf(ky[k], s, kv);
    }
    kv += __shfl_xor(kv, 1, 64);
    u = (1.0f / NPTS) / (kv + 1e-16f);
    if (h == 0) s_u[p] = u;

    const int ok = (fabsf(u - u1) <= UTOL * u) ? 1 : 0;
    u1 = u;
    const int allok = __syncthreads_and(ok);   // doubles as end-of-iter barrier
    if (allok && allok_prev) break;
    allok_prev = allok;
  }

  // ======== epilogue ========
  float wd = 0.0f;
  #pragma unroll
  for (int k = 0; k < ROWS_T; ++k) {
    const int ko = r0 + k;
    const int j  = jn - 3 + ko;
    const float cy = 8.0f * j + 4.0f;
    const float yd = (m2y * cy + y2) + cy * cy;
    const float* vrow = &s_v[rowb[k]];
    float acc = 0.0f;
    #pragma unroll
    for (int i = 0; i < WIN; ++i) {
      const int ii = in0 - 3 + i;
      const float cx = 8.0f * ii + 4.0f;
      const float xd = (m2x * cx + x2) + cx * cx;
      acc = fmaf((yd + xd) * (ky[k] * kx[i]), vrow[colc[i]], acc);
    }
    wd += acc;
  }

  double red[4];
  red[0] = (double)wd * (double)u;
  red[1] = 0.0; red[2] = 0.0; red[3] = 0.0;
  {
    const float4 pr4 = *reinterpret_cast<const float4*>(&pred_g[c0]);
    const float nmv[4] = {nm.x, nm.y, nm.z, nm.w};
    const float prv[4] = {pr4.x, pr4.y, pr4.z, pr4.w};
    #pragma unroll
    for (int q = 0; q < CPT; ++q) {
      const float beta = 10.0f * logf(s_v[c0 + q]);
      red[1] += (double)nmv[q] * (double)beta;   // ot_obj
      red[2] += (double)prv[q];                  // sc
      red[3] += (double)prv[q] * (double)beta;   // sb
    }
  }
  block_reduce4(red, s_red, tid, lane, wid);

  if (tid == 0) {
    const double sc = red[2], sb = red[3];
    const double denom = sc * sc + 1e-8;
    const double k1 = sc / denom, k2 = sb / denom;
    const double loss = k1 * sb - k2 * sc;   // == sum pred*(k1*beta-k2), ~0
    atomicAdd(out + 0, (float)loss);
    atomicAdd(out + 1, (float)red[0]);
    atomicAdd(out + 2, (float)red[1]);
  }
}

extern "C" void kernel_launch(void* const* d_in, const int* in_sizes, int n_in,
                              void* d_out, int out_size, void* d_ws, size_t ws_size,
                              hipStream_t stream) {
  const float* pred   = (const float*)d_in[0];
  const float* normed = (const float*)d_in[1];
  const float* pts    = (const float*)d_in[2];
  float* outp = (float*)d_out;
  const int B = in_sizes[0] / GRID;

  hipMemsetAsync(d_out, 0, (size_t)out_size * sizeof(float), stream);
  ot_loss_kernel<<<B, THREADS, 0, stream>>>(pred, normed, pts, outp);
}